// Round 3
// baseline (624.026 us; speedup 1.0000x reference)
//
#include <hip/hip_runtime.h>

typedef __attribute__((ext_vector_type(8))) short short8;
typedef __attribute__((ext_vector_type(4))) float f32x4;

#define NSTEPS 16

__device__ __forceinline__ unsigned short bf16rne(float f) {
  unsigned int u = __float_as_uint(f);
  u += 0x7FFFu + ((u >> 16) & 1u);
  return (unsigned short)(u >> 16);
}

// Single hardware instr (v_cvt_pk_bf16_f32), RNE. No builtin on gfx950.
__device__ __forceinline__ unsigned int pk2(float a, float b) {
  unsigned int r;
  asm("v_cvt_pk_bf16_f32 %0, %1, %2" : "=v"(r) : "v"(a), "v"(b));
  return r;
}

__device__ __forceinline__ float tanh_fast(float x) {
  // tanh(x) = 1 - 2/(e^{2x}+1); e->inf => 1, e->0 => -1 (no clamp needed)
  float e = __builtin_amdgcn_exp2f(x * 2.8853900817779268f);
  return __builtin_fmaf(-2.0f, __builtin_amdgcn_rcpf(e + 1.0f), 1.0f);
}

// Pre-shuffle fp32 weights -> bf16 MFMA fragments (B-frag of W == A-frag of W^T).
// lane holds W[k = 32*ks + 8*(lane>>4) + j][c = 16*t + (lane&15)], j=0..7
__global__ void ffjord_setup(const float* __restrict__ W1a, const float* __restrict__ W2a,
                             const float* __restrict__ W3a, const float* __restrict__ W1b,
                             const float* __restrict__ W2b, const float* __restrict__ W3b,
                             unsigned short* __restrict__ ws) {
  int gid = blockIdx.x * blockDim.x + threadIdx.x;   // 0..24575
  int bij = gid / 12288;
  int r = gid - bij * 12288;
  const float* W1 = bij ? W1b : W1a;
  const float* W2 = bij ? W2b : W2a;
  const float* W3 = bij ? W3b : W3a;
  unsigned short* o = ws + bij * 98304;
  const float* src;
  int kstride;
  if (r < 2048) {                 // W1f
    int lane = r & 63, nt = (r >> 6) & 15, ks = r >> 10;
    int k0 = ks * 32 + (lane >> 4) * 8, n = nt * 16 + (lane & 15);
    src = W1 + k0 * 256 + n; kstride = 256; o += r * 8;
  } else if (r < 10240) {         // W2f
    int rr = r - 2048;
    int lane = rr & 63, nt = (rr >> 6) & 15, ks = rr >> 10;
    int k0 = ks * 32 + (lane >> 4) * 8, n = nt * 16 + (lane & 15);
    src = W2 + k0 * 256 + n; kstride = 256; o += 16384 + rr * 8;
  } else {                        // W3f
    int rr = r - 10240;
    int lane = rr & 63, nt = (rr >> 6) & 3, ks = rr >> 8;
    int k0 = ks * 32 + (lane >> 4) * 8, n = nt * 16 + (lane & 15);
    src = W3 + k0 * 64 + n; kstride = 64; o += 81920 + rr * 8;
  }
  #pragma unroll
  for (int j = 0; j < 8; j++) o[j] = bf16rne(src[j * kstride]);
}

// Composed-operator setup: M2[a][c] = sum_d W3[a][d]*W1[d][c]  (256x256, fp32
// accumulate, one bf16 rounding) emitted directly as W2-style MFMA frags at
// ws+196608 (+bij*65536); cb3[c] = sum_d W1[d][c]*b3[d] as f32 at ws+327680.
__global__ void ffjord_setup2(const float* __restrict__ W1a, const float* __restrict__ W3a,
                              const float* __restrict__ b3a, const float* __restrict__ W1b,
                              const float* __restrict__ W3b, const float* __restrict__ b3b,
                              unsigned short* __restrict__ ws) {
  int bid = blockIdx.x;
  int tid = threadIdx.x;
  if (bid < 64) {
    int gid = bid * 4 + (tid >> 6);  // 0..255 = 2 bij x 8 ks x 16 t
    int bij = gid >> 7;
    int rem = gid & 127;
    int ks = rem >> 4;
    int t = rem & 15;
    int lane = tid & 63;
    const float* W1 = bij ? W1b : W1a;
    const float* W3 = bij ? W3b : W3a;
    int c = t * 16 + (lane & 15);
    int kb = ks * 32 + (lane >> 4) * 8;
    float acc[8];
    #pragma unroll
    for (int j = 0; j < 8; j++) acc[j] = 0.f;
    for (int d = 0; d < 64; d++) {
      float w1d = W1[d * 256 + c];
      #pragma unroll
      for (int j = 0; j < 8; j++)
        acc[j] = __builtin_fmaf(W3[(kb + j) * 64 + d], w1d, acc[j]);
    }
    unsigned short* o = ws + 196608 + bij * 65536 + ((ks * 16 + t) * 64 + lane) * 8;
    #pragma unroll
    for (int j = 0; j < 8; j++) o[j] = bf16rne(acc[j]);
  } else {
    // cb3: 512 values (2 bij x 256)
    for (int v = tid; v < 512; v += 256) {
      int bij = v >> 8, c = v & 255;
      const float* W1 = bij ? W1b : W1a;
      const float* b3 = bij ? b3b : b3a;
      float a = 0.f;
      for (int d = 0; d < 64; d++) a = __builtin_fmaf(W1[d * 256 + c], b3[d], a);
      ((float*)(ws + 327680))[v] = a;
    }
  }
}

// 2-phase stage loop via operator composition: track u_j = W1^T k_j instead of
// z. Phase A: h2 = tanh(W2^T h1 + b2) (broadcast). Phase B: u = M2^T h2 + cb3
// (wave-LOCAL, no transpose round-trip) + side k = W3^T h2 (waves 0-3, shares
// h2 B-frags, feeds yc immediately; skipped at s=1 since BW1=0); then
// h1_{s+1} = tanh(uy + h*sum a_j u_j + b1 + t*w1t) written to LDS.
// 2 barriers/stage (was 3). Real L1-from-z MFMA only at bijector entry.
// 512 threads / 8 waves, 2 out-tiles per wave; W2/M frags in registers
// (AGPR-parked), W3 frags in LDS.
__global__ __launch_bounds__(512, 2) void ffjord_main(
    const float* __restrict__ x, float* __restrict__ out,
    const unsigned short* __restrict__ ws,
    const float* __restrict__ W1a, const float* __restrict__ b1a,
    const float* __restrict__ b2a, const float* __restrict__ b3a,
    const float* __restrict__ W1b, const float* __restrict__ b1b,
    const float* __restrict__ b2b, const float* __restrict__ b3b) {
  __shared__ __align__(16) unsigned short zA[1088];
  __shared__ __align__(16) unsigned short h1A[4096];   // [g8][row16][j8]
  __shared__ __align__(16) unsigned short h2A[4096];
  __shared__ __align__(16) unsigned short w3s[2][16384]; // W3 frags, both bij

  const int tid = threadIdx.x;
  const int wave = tid >> 6;        // 0..7
  const int lane = tid & 63;
  const int cl = lane & 15;
  const int qd = lane >> 4;
  const int row0 = blockIdx.x * 16;

  const int tc0 = wave * 2, tc1 = tc0 + 1;
  const int c0 = wave * 32 + qd * 4;                   // tile-0 dim base
  const int hoff = wave * 512 + (qd >> 1) * 128 + cl * 8 + 4 * (qd & 1);
  const int zrb = qd * 136 + cl * 8;
  const int w3i = wave & 3;
  const int dl3 = w3i * 16 + qd * 4;
  const int zw = (2 * w3i + (qd >> 1)) * 136 + cl * 8 + 4 * (qd & 1);

  const float hstep = 1.0f / 16.0f;

  f32x4 yc;           // private y slice (4 dims x 1 row), waves 0-3

  const float A2[5][5] = {
      {1.f / 5.f, 0.f, 0.f, 0.f, 0.f},
      {3.f / 40.f, 9.f / 40.f, 0.f, 0.f, 0.f},
      {44.f / 45.f, -56.f / 15.f, 32.f / 9.f, 0.f, 0.f},
      {19372.f / 6561.f, -25360.f / 2187.f, 64448.f / 6561.f, -212.f / 729.f, 0.f},
      {9017.f / 3168.f, -355.f / 33.f, 46732.f / 5247.f, 49.f / 176.f, -5103.f / 18656.f}};
  const float CT[6] = {0.0f, 0.2f, 0.3f, 0.8f, 8.0f / 9.0f, 1.0f};
  const float BW0 = 35.f / 384.f, BW2 = 500.f / 1113.f, BW3 = 125.f / 192.f,
              BW4 = -2187.f / 6784.f, BW5 = 11.f / 84.f;
  // per-stage y/uy accumulation weight (h * b_s); BW1 = 0 -> stage 1 skipped
  const float HBW[6] = {hstep * BW0, 0.f, hstep * BW2, hstep * BW3,
                        hstep * BW4, hstep * BW5};

  // W3 fragments for BOTH bijectors -> LDS (2 x 2048 uint4)
  {
    const uint4* s0 = (const uint4*)(ws + 81920);
    const uint4* s1 = (const uint4*)(ws + 98304 + 81920);
    uint4* d0 = (uint4*)&w3s[0][0];
    uint4* d1 = (uint4*)&w3s[1][0];
    #pragma unroll
    for (int i = 0; i < 4; i++) {
      d0[tid + i * 512] = s0[tid + i * 512];
      d1[tid + i * 512] = s1[tid + i * 512];
    }
  }

  for (int bij = 0; bij < 2; bij++) {
    const unsigned short* wsb = ws + bij * 98304;
    const float* W1 = bij ? W1b : W1a;
    const float* b1 = bij ? b1b : b1a;
    const float* b2 = bij ? b2b : b2a;
    const float* b3 = bij ? b3b : b3a;

    f32x4 b1c0 = *(const f32x4*)(b1 + c0);
    f32x4 b1c1 = *(const f32x4*)(b1 + c0 + 16);
    f32x4 w1t0 = *(const f32x4*)(W1 + 64 * 256 + c0);
    f32x4 w1t1 = *(const f32x4*)(W1 + 64 * 256 + c0 + 16);
    f32x4 b2c0 = *(const f32x4*)(b2 + c0);
    f32x4 b2c1 = *(const f32x4*)(b2 + c0 + 16);
    f32x4 cb3c0 = *(const f32x4*)((const float*)(ws + 327680) + bij * 256 + c0);
    f32x4 cb3c1 = *(const f32x4*)((const float*)(ws + 327680) + bij * 256 + c0 + 16);
    f32x4 b3c = *(const f32x4*)(b3 + dl3);

    // register-resident W2 and M2 fragments for both out-tiles (AGPR-friendly)
    const short8* w2p = (const short8*)(wsb + 16384);
    const short8* mp = (const short8*)(ws + 196608 + bij * 65536);
    short8 w2f0[8], w2f1[8], mf0[8], mf1[8];
    #pragma unroll
    for (int ks = 0; ks < 8; ks++) {
      w2f0[ks] = w2p[(ks * 16 + tc0) * 64 + lane];
      w2f1[ks] = w2p[(ks * 16 + tc1) * 64 + lane];
      mf0[ks] = mp[(ks * 16 + tc0) * 64 + lane];
      mf1[ks] = mp[(ks * 16 + tc1) * 64 + lane];
    }
    const short8* w3c = (const short8*)&w3s[bij][0];

    // ---- bijector entry: publish z0=y frags; uy = W1s^T y; h1_0 = tanh(uy+b1)
    if (wave < 4) {
      if (bij == 0) yc = *(const f32x4*)(x + (row0 + cl) * 64 + dl3);
      uint2 pv;
      pv.x = pk2(yc[0], yc[1]);
      pv.y = pk2(yc[2], yc[3]);
      *(uint2*)(zA + zw) = pv;
    }
    __syncthreads();

    f32x4 uy0, uy1;
    {
      const short8* w1p = (const short8*)wsb;
      short8 wA0 = w1p[(0 * 16 + tc0) * 64 + lane];
      short8 wA1 = w1p[(1 * 16 + tc0) * 64 + lane];
      short8 wB0 = w1p[(0 * 16 + tc1) * 64 + lane];
      short8 wB1 = w1p[(1 * 16 + tc1) * 64 + lane];
      short8 a0 = *(const short8*)(zA + zrb);
      short8 a1 = *(const short8*)(zA + zrb + 544);
      f32x4 r0, r1;
      #pragma unroll
      for (int r = 0; r < 4; r++) { r0[r] = 0.f; r1[r] = 0.f; }
      r0 = __builtin_amdgcn_mfma_f32_16x16x32_bf16(wA0, a0, r0, 0, 0, 0);
      r1 = __builtin_amdgcn_mfma_f32_16x16x32_bf16(wB0, a0, r1, 0, 0, 0);
      r0 = __builtin_amdgcn_mfma_f32_16x16x32_bf16(wA1, a1, r0, 0, 0, 0);
      r1 = __builtin_amdgcn_mfma_f32_16x16x32_bf16(wB1, a1, r1, 0, 0, 0);
      uy0 = r0;
      uy1 = r1;
      // t=0 at bijector entry (step 0, c=0)
      uint2 pv0, pv1;
      pv0.x = pk2(tanh_fast(r0[0] + b1c0[0]), tanh_fast(r0[1] + b1c0[1]));
      pv0.y = pk2(tanh_fast(r0[2] + b1c0[2]), tanh_fast(r0[3] + b1c0[3]));
      pv1.x = pk2(tanh_fast(r1[0] + b1c1[0]), tanh_fast(r1[1] + b1c1[1]));
      pv1.y = pk2(tanh_fast(r1[2] + b1c1[2]), tanh_fast(r1[3] + b1c1[3]));
      *(uint2*)(h1A + hoff) = pv0;
      *(uint2*)(h1A + hoff + 256) = pv1;
    }
    __syncthreads();

    for (int step = 0; step < NSTEPS; step++) {
      float stepf = (float)step;
      f32x4 uh0[5], uh1[5];   // u history (this step), registers, static idx
      #pragma unroll
      for (int s = 0; s < 6; s++) {
        // ---- phase A: h2 = tanh(W2^T h1 + b2), K=256, 2 tiles/wave
        {
          f32x4 aA0 = b2c0, aA1 = b2c1;
          f32x4 aB0, aB1;
          #pragma unroll
          for (int r = 0; r < 4; r++) { aB0[r] = 0.f; aB1[r] = 0.f; }
          #pragma unroll
          for (int ks = 0; ks < 4; ks++) {
            short8 hb = ((const short8*)h1A)[ks * 64 + lane];
            aA0 = __builtin_amdgcn_mfma_f32_16x16x32_bf16(w2f0[ks], hb, aA0, 0, 0, 0);
            aA1 = __builtin_amdgcn_mfma_f32_16x16x32_bf16(w2f1[ks], hb, aA1, 0, 0, 0);
          }
          #pragma unroll
          for (int ks = 4; ks < 8; ks++) {
            short8 hb = ((const short8*)h1A)[ks * 64 + lane];
            aB0 = __builtin_amdgcn_mfma_f32_16x16x32_bf16(w2f0[ks], hb, aB0, 0, 0, 0);
            aB1 = __builtin_amdgcn_mfma_f32_16x16x32_bf16(w2f1[ks], hb, aB1, 0, 0, 0);
          }
          uint2 pv0, pv1;
          pv0.x = pk2(tanh_fast(aA0[0] + aB0[0]), tanh_fast(aA0[1] + aB0[1]));
          pv0.y = pk2(tanh_fast(aA0[2] + aB0[2]), tanh_fast(aA0[3] + aB0[3]));
          pv1.x = pk2(tanh_fast(aA1[0] + aB1[0]), tanh_fast(aA1[1] + aB1[1]));
          pv1.y = pk2(tanh_fast(aA1[2] + aB1[2]), tanh_fast(aA1[3] + aB1[3]));
          *(uint2*)(h2A + hoff) = pv0;
          *(uint2*)(h2A + hoff + 256) = pv1;
        }
        __syncthreads();

        // ---- phase B: u_s = M2^T h2 + cb3 (all waves, wave-local);
        // side k_s = W3^T h2 + b3 (waves 0-3, shared h2 B-frags) -> yc;
        // then h1_{s+1} = tanh(uy + h*sum a_j u_j + b1 + t_{s+1}*w1t)
        {
          f32x4 uA0 = cb3c0, uA1 = cb3c1;
          f32x4 uB0, uB1;
          #pragma unroll
          for (int r = 0; r < 4; r++) { uB0[r] = 0.f; uB1[r] = 0.f; }
          f32x4 accP, accQ;
          const bool dok = (s != 1);   // BW1 = 0 -> k at s=1 never used
          if (dok && wave < 4) {
            accP = b3c;
            #pragma unroll
            for (int r = 0; r < 4; r++) accQ[r] = 0.f;
          }
          #pragma unroll
          for (int ks = 0; ks < 8; ks++) {
            short8 hb = ((const short8*)h2A)[ks * 64 + lane];
            if (ks < 4) {
              uA0 = __builtin_amdgcn_mfma_f32_16x16x32_bf16(mf0[ks], hb, uA0, 0, 0, 0);
              uA1 = __builtin_amdgcn_mfma_f32_16x16x32_bf16(mf1[ks], hb, uA1, 0, 0, 0);
            } else {
              uB0 = __builtin_amdgcn_mfma_f32_16x16x32_bf16(mf0[ks], hb, uB0, 0, 0, 0);
              uB1 = __builtin_amdgcn_mfma_f32_16x16x32_bf16(mf1[ks], hb, uB1, 0, 0, 0);
            }
            if (dok && wave < 4) {
              short8 wf = w3c[(ks * 4 + w3i) * 64 + lane];
              if ((ks & 1) == 0)
                accP = __builtin_amdgcn_mfma_f32_16x16x32_bf16(wf, hb, accP, 0, 0, 0);
              else
                accQ = __builtin_amdgcn_mfma_f32_16x16x32_bf16(wf, hb, accQ, 0, 0, 0);
            }
          }
          f32x4 uc0, uc1;
          #pragma unroll
          for (int r = 0; r < 4; r++) {
            uc0[r] = uA0[r] + uB0[r];
            uc1[r] = uA1[r] + uB1[r];
          }
          if (dok && wave < 4) {
            #pragma unroll
            for (int r = 0; r < 4; r++)
              yc[r] = __builtin_fmaf(HBW[s], accP[r] + accQ[r], yc[r]);
          }

          float tnext = (s < 5) ? (stepf + CT[s + 1]) * hstep
                                : (stepf + 1.0f) * hstep;
          f32x4 p0, p1;
          if (s < 5) {
            uh0[s] = uc0;
            uh1[s] = uc1;
            float ad = hstep * A2[s][s];
            #pragma unroll
            for (int r = 0; r < 4; r++) {
              p0[r] = __builtin_fmaf(tnext, w1t0[r], b1c0[r]) + uy0[r];
              p1[r] = __builtin_fmaf(tnext, w1t1[r], b1c1[r]) + uy1[r];
              p0[r] = __builtin_fmaf(ad, uc0[r], p0[r]);
              p1[r] = __builtin_fmaf(ad, uc1[r], p1[r]);
            }
            #pragma unroll
            for (int j = 0; j < 4; j++)
              if (j < s) {
                float a = hstep * A2[s][j];
                #pragma unroll
                for (int r = 0; r < 4; r++) {
                  p0[r] = __builtin_fmaf(a, uh0[j][r], p0[r]);
                  p1[r] = __builtin_fmaf(a, uh1[j][r], p1[r]);
                }
              }
          } else {
            // end of step: uy <- uy + h*sum b_i u_i; pre = uy' + b1 + t*w1t
            #pragma unroll
            for (int r = 0; r < 4; r++) {
              float d0 = __builtin_fmaf(BW0, uh0[0][r],
                         __builtin_fmaf(BW2, uh0[2][r],
                         __builtin_fmaf(BW3, uh0[3][r],
                         __builtin_fmaf(BW4, uh0[4][r], BW5 * uc0[r]))));
              float d1 = __builtin_fmaf(BW0, uh1[0][r],
                         __builtin_fmaf(BW2, uh1[2][r],
                         __builtin_fmaf(BW3, uh1[3][r],
                         __builtin_fmaf(BW4, uh1[4][r], BW5 * uc1[r]))));
              uy0[r] = __builtin_fmaf(hstep, d0, uy0[r]);
              uy1[r] = __builtin_fmaf(hstep, d1, uy1[r]);
              p0[r] = __builtin_fmaf(tnext, w1t0[r], b1c0[r]) + uy0[r];
              p1[r] = __builtin_fmaf(tnext, w1t1[r], b1c1[r]) + uy1[r];
            }
          }
          uint2 pv0, pv1;
          pv0.x = pk2(tanh_fast(p0[0]), tanh_fast(p0[1]));
          pv0.y = pk2(tanh_fast(p0[2]), tanh_fast(p0[3]));
          pv1.x = pk2(tanh_fast(p1[0]), tanh_fast(p1[1]));
          pv1.y = pk2(tanh_fast(p1[2]), tanh_fast(p1[3]));
          *(uint2*)(h1A + hoff) = pv0;
          *(uint2*)(h1A + hoff + 256) = pv1;
        }
        __syncthreads();
      } // stages
    } // steps
  } // bijectors

  if (wave < 4)
    *(f32x4*)(out + (row0 + cl) * 64 + dl3) = yc;
}

extern "C" void kernel_launch(void* const* d_in, const int* in_sizes, int n_in,
                              void* d_out, int out_size, void* d_ws, size_t ws_size,
                              hipStream_t stream) {
  (void)in_sizes; (void)n_in; (void)out_size; (void)ws_size;
  const float* x   = (const float*)d_in[0];
  const float* W1a = (const float*)d_in[1];
  const float* b1a = (const float*)d_in[2];
  const float* W2a = (const float*)d_in[3];
  const float* b2a = (const float*)d_in[4];
  const float* W3a = (const float*)d_in[5];
  const float* b3a = (const float*)d_in[6];
  const float* W1b = (const float*)d_in[7];
  const float* b1b = (const float*)d_in[8];
  const float* W2b = (const float*)d_in[9];
  const float* b2b = (const float*)d_in[10];
  const float* W3b = (const float*)d_in[11];
  const float* b3b = (const float*)d_in[12];
  unsigned short* ws = (unsigned short*)d_ws;
  float* out = (float*)d_out;

  hipLaunchKernelGGL(ffjord_setup, dim3(96), dim3(256), 0, stream,
                     W1a, W2a, W3a, W1b, W2b, W3b, ws);
  hipLaunchKernelGGL(ffjord_setup2, dim3(65), dim3(256), 0, stream,
                     W1a, W3a, b3a, W1b, W3b, b3b, ws);
  hipLaunchKernelGGL(ffjord_main, dim3(256), dim3(512), 0, stream,
                     x, out, ws, W1a, b1a, b2a, b3a, W1b, b1b, b2b, b3b);
}